// Round 1
// baseline (2220.028 us; speedup 1.0000x reference)
//
#include <hip/hip_runtime.h>

// Problem: act[n,b,o] = (sum_i x[b,i]*W[i,o]*(noise[n,i,o]-1)) / r[b,o]
//          r[b,o]     = sqrt(sum_i x[b,i]^2 * W[i,o]^2)
// (column norms of W cancel exactly between numerator and denominator)
//
// B=128, IN=784 (=49*16), OUT=1024, NITER=500. Memory-bound: noise = 1.605 GB.
// Roofline: (1.606 GB read + 0.262 GB write) / 6.3 TB/s ~= 296 us.
//
// This revision: noise is staged through LDS with double-buffered
// global_load_lds (width 16) and prefetch-1, block covers a 256-wide o-tile
// (1 KB contiguous per noise row) with 8 waves. Fragment layouts and math
// identical to the previously verified kernel.

#define B_DIM   128
#define IN_DIM  784
#define OUT_DIM 1024
#define NITER   500
#define KSTEPS  49      // 784 / 16 (one K-step consumes 16 noise rows)
#define KK_DIM  98      // 784 / 8  (8-row groups; lane's frag = 8 consecutive k)
#define OW      256     // o-width per block

typedef __attribute__((ext_vector_type(8)))  short short8;
typedef __attribute__((ext_vector_type(4)))  float floatx4;
typedef __attribute__((ext_vector_type(16))) float floatx16;

// f32 -> bf16 round-to-nearest-even (3 VALU ops, no header dependency)
__device__ __forceinline__ short f2bf(float f) {
    unsigned u = __builtin_bit_cast(unsigned, f);
    unsigned r = (u + 0x7FFFu + ((u >> 16) & 1u)) >> 16;
    return (short)(unsigned short)r;
}

// ---- precompute: x in fragment-ordered bf16 (and x^2 for the r-GEMM) ----
// layout xf[(kk*128 + m)*8 + j] = bf16(x[m][kk*8+j]) ; 16B per (kk,m) chunk
__global__ void __launch_bounds__(256) prep_x_kernel(const float* __restrict__ x,
                                                     short* __restrict__ xf,
                                                     short* __restrict__ x2f) {
    int tid = blockIdx.x * 256 + threadIdx.x;        // 98*128 = 12544 threads
    if (tid >= KK_DIM * B_DIM) return;
    int m  = tid & (B_DIM - 1);
    int kk = tid >> 7;
    int src = m * IN_DIM + kk * 8;
    int dst = (kk * B_DIM + m) * 8;
#pragma unroll
    for (int j = 0; j < 8; ++j) {
        float v = x[src + j];
        xf[dst + j]  = f2bf(v);
        x2f[dst + j] = f2bf(v * v);
    }
}

// ---- precompute: W fragment-ordered f32 (and W^2 bf16 for the r-GEMM) ----
// layout Wf[(kk*1024 + o)*8 + j] = W[kk*8+j][o]
__global__ void __launch_bounds__(256) prep_w_kernel(const float* __restrict__ W,
                                                     float* __restrict__ Wf,
                                                     short* __restrict__ W2f) {
    int tid = blockIdx.x * 256 + threadIdx.x;        // 98*1024 = 100352 threads
    if (tid >= KK_DIM * OUT_DIM) return;
    int o  = tid & (OUT_DIM - 1);
    int kk = tid >> 10;
    int dst = (kk * OUT_DIM + o) * 8;
#pragma unroll
    for (int j = 0; j < 8; ++j) {
        float v = W[(kk * 8 + j) * OUT_DIM + o];
        Wf[dst + j]  = v;
        W2f[dst + j] = f2bf(v * v);
    }
}

// ---- r-GEMM: invr[b,o] = rsqrt( (x^2) @ (W^2) ), via 32x32x16 bf16 MFMA ----
__global__ void __launch_bounds__(256) rnorm_kernel(const short* __restrict__ x2f,
                                                    const short* __restrict__ w2f,
                                                    float* __restrict__ invr) {
    int ot   = blockIdx.x;                 // 8 o-tiles of 128
    int tid  = threadIdx.x;
    int wave = tid >> 6, lane = tid & 63;
    int wm = wave & 1, wn = wave >> 1;
    int p = lane & 31, h = lane >> 5;
    int m_base = wm * 64;
    int o_base = ot * 128 + wn * 64;

    floatx16 acc[2][2] = {};
    for (int ks = 0; ks < KSTEPS; ++ks) {
        int kk = ks * 2 + h;
        short8 a[2], b[2];
#pragma unroll
        for (int mt = 0; mt < 2; ++mt)
            a[mt] = *(const short8*)(x2f + (kk * B_DIM + m_base + mt * 32 + p) * 8);
#pragma unroll
        for (int nt = 0; nt < 2; ++nt)
            b[nt] = *(const short8*)(w2f + (kk * OUT_DIM + o_base + nt * 32 + p) * 8);
#pragma unroll
        for (int mt = 0; mt < 2; ++mt)
#pragma unroll
            for (int nt = 0; nt < 2; ++nt)
                acc[mt][nt] = __builtin_amdgcn_mfma_f32_32x32x16_bf16(a[mt], b[nt], acc[mt][nt], 0, 0, 0);
    }
#pragma unroll
    for (int mt = 0; mt < 2; ++mt)
#pragma unroll
        for (int nt = 0; nt < 2; ++nt)
#pragma unroll
            for (int reg = 0; reg < 16; ++reg) {
                int r   = (reg & 3) + 8 * (reg >> 2) + 4 * h;   // measured C/D layout
                int row = m_base + mt * 32 + r;
                int col = o_base + nt * 32 + p;
                invr[row * OUT_DIM + col] = rsqrtf(acc[mt][nt][reg]);
            }
}

// ---- main: act[n] = (x @ (W .* (noise[n]-1))) * invr ----
// 512 threads = 8 waves (2 m-rows x 4 o-cols of 64x64 wave tiles), o-tile 256.
// noise: global_load_lds dwordx4 -> LDS double buffer, prefetch-1.
__global__ void __launch_bounds__(512, 2)
wnorm_main_kernel(const short* __restrict__ xf,
                  const float* __restrict__ Wf,
                  const float* __restrict__ noise,
                  const float* __restrict__ invr,
                  float* __restrict__ out) {
    __shared__ float nbuf[2][16][OW];       // 2 x 16 rows x 256 cols f32 = 32 KB

    int bx = blockIdx.x;
    int ot = bx & 3;          // o-tile fast -> spreads one n's 4 tiles across XCDs
    int n  = bx >> 2;
    int o_blk = ot * OW;

    int tid  = threadIdx.x;
    int wave = tid >> 6, lane = tid & 63;
    int wm = wave & 1, wn = wave >> 1;
    int p = lane & 31, h = lane >> 5;
    int m_base = wm * 64;
    int c_loc  = wn * 64 + p;               // col within block tile (+nt*32)
    int o_w    = o_blk + c_loc;             // global col (+nt*32)

    const float* nbase = noise + (size_t)n * (IN_DIM * OUT_DIM);

    // stage K-step `ks` (16 rows x 256 cols f32) into nbuf[buf]:
    // each wave stages 2 rows; one global_load_lds = 64 lanes x 16 B = 1 row
    // (1 KB contiguous in HBM). LDS dest is wave-uniform base + lane*16 (linear).
    auto stage = [&](int buf, int ks) {
#pragma unroll
        for (int q = 0; q < 2; ++q) {
            int r = wave * 2 + q;
            const float* g = nbase + (size_t)(ks * 16 + r) * OUT_DIM + o_blk + lane * 4;
            __builtin_amdgcn_global_load_lds(
                (const __attribute__((address_space(1))) unsigned*)g,
                (__attribute__((address_space(3))) unsigned*)&nbuf[buf][r][0],
                16, 0, 0);
        }
    };

    floatx16 acc[2][2] = {};

    stage(0, 0);
    __syncthreads();                        // compiler drains vmcnt before barrier

    int cur = 0;
#pragma unroll 1
    for (int ks = 0; ks < KSTEPS; ++ks) {
        if (ks + 1 < KSTEPS) stage(cur ^ 1, ks + 1);   // prefetch next K-step

        int kk = ks * 2 + h;
        // b' = bf16( W * (noise - 1) ) = bf16( fma(W, noise, -W) )
        short8 bfr[2];
#pragma unroll
        for (int nt = 0; nt < 2; ++nt) {
            const float* wp = Wf + ((size_t)kk * OUT_DIM + o_w + nt * 32) * 8;
            floatx4 w0 = *(const floatx4*)(wp);
            floatx4 w1 = *(const floatx4*)(wp + 4);
            short8 t;
#pragma unroll
            for (int j = 0; j < 4; ++j) {
                // LDS read: bank = (c_loc+nt*32)%32 = p -> conflict-free (2-way
                // h-alias across half-waves is free)
                float nlo = nbuf[cur][h * 8 + j    ][c_loc + nt * 32];
                float nhi = nbuf[cur][h * 8 + j + 4][c_loc + nt * 32];
                t[j]     = f2bf(fmaf(w0[j], nlo, -w0[j]));
                t[j + 4] = f2bf(fmaf(w1[j], nhi, -w1[j]));
            }
            bfr[nt] = t;
        }
        short8 a[2];
#pragma unroll
        for (int mt = 0; mt < 2; ++mt)
            a[mt] = *(const short8*)(xf + ((size_t)kk * B_DIM + m_base + mt * 32 + p) * 8);
#pragma unroll
        for (int mt = 0; mt < 2; ++mt)
#pragma unroll
            for (int nt = 0; nt < 2; ++nt)
                acc[mt][nt] = __builtin_amdgcn_mfma_f32_32x32x16_bf16(a[mt], bfr[nt], acc[mt][nt], 0, 0, 0);

        __syncthreads();   // drains prefetch vmcnt + lgkm; makes next buffer safe
        cur ^= 1;
    }

    // epilogue: scale by invr (L2-resident), nontemporal store (never re-read)
#pragma unroll
    for (int mt = 0; mt < 2; ++mt)
#pragma unroll
        for (int nt = 0; nt < 2; ++nt) {
            floatx16 av = acc[mt][nt];
#pragma unroll
            for (int reg = 0; reg < 16; ++reg) {
                int rr  = (reg & 3) + 8 * (reg >> 2) + 4 * h;   // measured C/D layout
                int row = m_base + mt * 32 + rr;
                int col = o_w + nt * 32;
                float val = av[reg] * invr[row * OUT_DIM + col];
                __builtin_nontemporal_store(val, out + (size_t)(n * B_DIM + row) * OUT_DIM + col);
            }
        }
}

extern "C" void kernel_launch(void* const* d_in, const int* in_sizes, int n_in,
                              void* d_out, int out_size, void* d_ws, size_t ws_size,
                              hipStream_t stream) {
    const float* x     = (const float*)d_in[0];   // [128, 784]
    const float* W     = (const float*)d_in[1];   // [784, 1024]
    const float* noise = (const float*)d_in[2];   // [500, 784, 1024]
    float* out = (float*)d_out;                   // [500*128, 1024]

    // workspace layout (needs ~5.75 MB)
    char* ws = (char*)d_ws;
    short* xf   = (short*)(ws);                   // 98*128*8 bf16  = 200704 B
    short* x2f  = (short*)(ws + 200704);          // 200704 B
    float* Wf   = (float*)(ws + 401408);          // 98*1024*8 f32  = 3211264 B
    short* W2f  = (short*)(ws + 3612672);         // 1605632 B
    float* invr = (float*)(ws + 5218304);         // 128*1024 f32   = 524288 B

    prep_x_kernel<<<dim3(49),   dim3(256), 0, stream>>>(x, xf, x2f);
    prep_w_kernel<<<dim3(392),  dim3(256), 0, stream>>>(W, Wf, W2f);
    rnorm_kernel <<<dim3(8),    dim3(256), 0, stream>>>(x2f, W2f, invr);
    wnorm_main_kernel<<<dim3(500 * 4), dim3(512), 0, stream>>>(xf, Wf, noise, invr, out);
}